// Round 1
// baseline (480.231 us; speedup 1.0000x reference)
//
#include <hip/hip_runtime.h>

#define N_NODES 8192
#define IN_F 512
#define OUT_F 64
#define LOG2E 1.4426950408889634f

typedef short bf16x8 __attribute__((ext_vector_type(8)));
typedef float f32x4 __attribute__((ext_vector_type(4)));

static __device__ __forceinline__ unsigned short f2bf(float f) {
  unsigned u = __float_as_uint(f);
  u = (u + 0x7fffu + ((u >> 16) & 1u)) >> 16;
  return (unsigned short)u;
}

// K1: h = input @ W  (one wave per row, lane = output col), plus
// f_srcL = (h@a[:64])*log2e, f_dstL = (h@a[64:])*log2e via wave reduction.
__global__ __launch_bounds__(256) void k_gemm(const float* __restrict__ input,
                                              const float* __restrict__ W,
                                              const float* __restrict__ a,
                                              float* __restrict__ h,
                                              float* __restrict__ fsrcL,
                                              float* __restrict__ fdstL) {
  const int lane = threadIdx.x & 63;
  const int wv = threadIdx.x >> 6;
  const int row = blockIdx.x * 4 + wv;
  const float* inrow = input + (size_t)row * IN_F;
  const int c = lane;
  float acc = 0.f;
  for (int k = 0; k < IN_F; k += 4) {
    float4 x = *(const float4*)(inrow + k);
    acc += x.x * W[(k + 0) * OUT_F + c];
    acc += x.y * W[(k + 1) * OUT_F + c];
    acc += x.z * W[(k + 2) * OUT_F + c];
    acc += x.w * W[(k + 3) * OUT_F + c];
  }
  h[(size_t)row * OUT_F + c] = acc;
  float vs = acc * a[c];
  float vd = acc * a[OUT_F + c];
#pragma unroll
  for (int off = 32; off > 0; off >>= 1) {
    vs += __shfl_xor(vs, off, 64);
    vd += __shfl_xor(vd, off, 64);
  }
  if (lane == 0) {
    fsrcL[row] = vs * LOG2E;
    fdstL[row] = vd * LOG2E;
  }
}

// K1c: ML = max(f_dstL)  (single block)
__global__ __launch_bounds__(256) void k_max(const float* __restrict__ fdstL,
                                             float* __restrict__ ML) {
  float m = -3.0e38f;
  for (int i = threadIdx.x; i < N_NODES; i += 256) m = fmaxf(m, fdstL[i]);
#pragma unroll
  for (int off = 32; off > 0; off >>= 1) m = fmaxf(m, __shfl_xor(m, off, 64));
  __shared__ float sm[4];
  if ((threadIdx.x & 63) == 0) sm[threadIdx.x >> 6] = m;
  __syncthreads();
  if (threadIdx.x == 0) ML[0] = fmaxf(fmaxf(sm[0], sm[1]), fmaxf(sm[2], sm[3]));
}

// K1b: hT[c][r] = bf16(h[r][c])  — 64x64 tiles through padded LDS.
__global__ __launch_bounds__(256) void k_transpose(const float* __restrict__ h,
                                                   unsigned short* __restrict__ hT) {
  __shared__ float t[64][65];
  const int r0 = blockIdx.x * 64;
#pragma unroll
  for (int q = 0; q < 16; q++) {
    int idx = q * 256 + threadIdx.x;
    int r = idx >> 6, c = idx & 63;
    t[c][r] = h[(size_t)(r0 + r) * OUT_F + c];
  }
  __syncthreads();
#pragma unroll
  for (int q = 0; q < 8; q++) {
    int idx = q * 256 + threadIdx.x;
    int c = idx >> 5, rp = idx & 31;
    float a0 = t[c][2 * rp], a1 = t[c][2 * rp + 1];
    unsigned pk = (unsigned)f2bf(a0) | ((unsigned)f2bf(a1) << 16);
    *(unsigned*)(hT + (size_t)c * N_NODES + r0 + 2 * rp) = pk;
  }
}

// K2: attention. Block = 16 rows, 4 waves each covering 1/4 of the j-range.
// P computed directly in MFMA A-layout (m=lane&15, k=(lane>>4)*8+t).
// B frags loaded contiguously from transposed hT. C frags: 16 rows x 64 cols.
__global__ __launch_bounds__(256) void k_attn(const int* __restrict__ adj,
                                              const unsigned short* __restrict__ hT,
                                              const float* __restrict__ fsrcL,
                                              const float* __restrict__ fdstL,
                                              const float* __restrict__ MLp,
                                              float* __restrict__ out) {
  const int lane = threadIdx.x & 63;
  const int wv = threadIdx.x >> 6;
  const int i0 = blockIdx.x * 16;
  const int m = lane & 15;   // A-row / B-col index
  const int g = lane >> 4;   // k-group 0..3

  const float MLv = MLp[0];
  const float fs = fsrcL[i0 + m];
  const float xm = fs + MLv;
  const float mL = fmaxf(xm, 0.2f * xm);  // fixed per-row max (log2-scaled)

  f32x4 acc0{}, acc1{}, acc2{}, acc3{};
  float lpart = 0.f;

  const int* adjrow = adj + (size_t)(i0 + m) * N_NODES;
  const unsigned short* hT0 = hT + (size_t)m * N_NODES;

  const int jbeg = wv * (N_NODES / 4);
  const int jend = jbeg + (N_NODES / 4);
  for (int j0 = jbeg; j0 < jend; j0 += 64) {
#pragma unroll
    for (int s = 0; s < 2; s++) {
      const int jb = j0 + s * 32 + g * 8;
      int4 a0 = *(const int4*)(adjrow + jb);
      int4 a1 = *(const int4*)(adjrow + jb + 4);
      float4 d0 = *(const float4*)(fdstL + jb);
      float4 d1 = *(const float4*)(fdstL + jb + 4);
      bf16x8 b0 = *(const bf16x8*)(hT0 + jb);
      bf16x8 b1 = *(const bf16x8*)(hT0 + (size_t)16 * N_NODES + jb);
      bf16x8 b2 = *(const bf16x8*)(hT0 + (size_t)32 * N_NODES + jb);
      bf16x8 b3 = *(const bf16x8*)(hT0 + (size_t)48 * N_NODES + jb);

      int av[8] = {a0.x, a0.y, a0.z, a0.w, a1.x, a1.y, a1.z, a1.w};
      float dv[8] = {d0.x, d0.y, d0.z, d0.w, d1.x, d1.y, d1.z, d1.w};
      bf16x8 pa;
#pragma unroll
      for (int t = 0; t < 8; t++) {
        float x = fs + dv[t];
        float y = fmaxf(x, 0.2f * x) - mL;
        float p = __builtin_amdgcn_exp2f(y);
        p = av[t] ? p : 0.0f;
        lpart += p;
        pa[t] = (short)f2bf(p);
      }
      acc0 = __builtin_amdgcn_mfma_f32_16x16x32_bf16(pa, b0, acc0, 0, 0, 0);
      acc1 = __builtin_amdgcn_mfma_f32_16x16x32_bf16(pa, b1, acc1, 0, 0, 0);
      acc2 = __builtin_amdgcn_mfma_f32_16x16x32_bf16(pa, b2, acc2, 0, 0, 0);
      acc3 = __builtin_amdgcn_mfma_f32_16x16x32_bf16(pa, b3, acc3, 0, 0, 0);
    }
  }

  // l: reduce across the 4 k-groups (lanes sharing m)
  lpart += __shfl_xor(lpart, 16, 64);
  lpart += __shfl_xor(lpart, 32, 64);

  __shared__ float accbuf[4][16][64];
  __shared__ float lbuf[4][16];
#pragma unroll
  for (int r = 0; r < 4; r++) {
    accbuf[wv][g * 4 + r][0 + m]  = acc0[r];
    accbuf[wv][g * 4 + r][16 + m] = acc1[r];
    accbuf[wv][g * 4 + r][32 + m] = acc2[r];
    accbuf[wv][g * 4 + r][48 + m] = acc3[r];
  }
  if (lane < 16) lbuf[wv][lane] = lpart;
  __syncthreads();

#pragma unroll
  for (int q = 0; q < 4; q++) {
    int idx = q * 256 + threadIdx.x;
    int r = idx >> 6, c = idx & 63;
    float ssum = accbuf[0][r][c] + accbuf[1][r][c] + accbuf[2][r][c] + accbuf[3][r][c];
    float l = lbuf[0][r] + lbuf[1][r] + lbuf[2][r] + lbuf[3][r];
    float v = ssum / l;
    out[(size_t)(i0 + r) * OUT_F + c] =
        v > 0.f ? v : __builtin_amdgcn_exp2f(v * LOG2E) - 1.f;
  }
}

extern "C" void kernel_launch(void* const* d_in, const int* in_sizes, int n_in,
                              void* d_out, int out_size, void* d_ws, size_t ws_size,
                              hipStream_t stream) {
  const float* input = (const float*)d_in[0];
  const int* adj = (const int*)d_in[1];
  const float* W = (const float*)d_in[2];
  const float* a = (const float*)d_in[3];
  float* out = (float*)d_out;

  char* ws = (char*)d_ws;
  float* h = (float*)ws;                                     // 2 MB
  unsigned short* hT = (unsigned short*)(ws + (2u << 20));   // 1 MB
  float* fsrcL = (float*)(ws + (3u << 20));                  // 32 KB
  float* fdstL = (float*)(ws + (3u << 20) + 32 * 1024);      // 32 KB
  float* ML = (float*)(ws + (3u << 20) + 64 * 1024);         // 4 B

  k_gemm<<<N_NODES / 4, 256, 0, stream>>>(input, W, a, h, fsrcL, fdstL);
  k_max<<<1, 256, 0, stream>>>(fdstL, ML);
  k_transpose<<<N_NODES / 64, 256, 0, stream>>>(h, hT);
  k_attn<<<N_NODES / 16, 256, 0, stream>>>(adj, hT, fsrcL, fdstL, ML, out);
}